// Round 1
// baseline (848.409 us; speedup 1.0000x reference)
//
#include <hip/hip_runtime.h>

#define BATCH 8
#define N 2048
#define NITERS 20

// ---------------------------------------------------------------------------
// Sinkhorn (log domain, uniform marginals) via dual potentials:
//   f_i = LSE_j(Z0_ij - g_j)          (row pass; also accumulates col sums)
//   g_j = log( sum_i exp(Z0_ij - f_i) )   (combine of per-wave partials)
// Output: exp(Z0 - f_i - g_j)
// Z0 = log_alpha / TAU with TAU = 1.0, so Z0 == input.
// ---------------------------------------------------------------------------

static __device__ __forceinline__ float wave_max(float v) {
#pragma unroll
  for (int o = 32; o > 0; o >>= 1) v = fmaxf(v, __shfl_xor(v, o, 64));
  return v;
}
static __device__ __forceinline__ float wave_sum(float v) {
#pragma unroll
  for (int o = 32; o > 0; o >>= 1) v += __shfl_xor(v, o, 64);
  return v;
}

__global__ void init_g_kernel(float* __restrict__ g) {
  const int i = blockIdx.x * blockDim.x + threadIdx.x;
  if (i < BATCH * N) g[i] = 0.f;
}

// One wave handles RPW consecutive rows of one batch; each lane owns 32 fixed
// columns (8 x float4). g kept in registers across the wave's rows. Writes
// per-wave column partial sums (exp(Z0 - f)) to `part` for the combine pass.
template <int RPW>
__global__ __launch_bounds__(256) void sink_row_kernel(
    const float* __restrict__ z0, const float* __restrict__ g,
    float* __restrict__ f, float* __restrict__ part) {
  constexpr int CH = N / RPW;  // chunks (waves) per batch
  const int lane = threadIdx.x & 63;
  const int w = threadIdx.x >> 6;
  const int b = blockIdx.y;
  const int chunk = blockIdx.x * 4 + w;  // 4 waves per block
  const int row0 = chunk * RPW;

  const float4* g4 = reinterpret_cast<const float4*>(g + (size_t)b * N);
  float4 gv[8], acc[8];
#pragma unroll
  for (int k = 0; k < 8; ++k) {
    gv[k] = g4[lane + 64 * k];
    acc[k] = make_float4(0.f, 0.f, 0.f, 0.f);
  }

  for (int r = 0; r < RPW; ++r) {
    const int row = row0 + r;
    const float4* z4 =
        reinterpret_cast<const float4*>(z0 + ((size_t)b * N + row) * N);
    float4 zv[8];
#pragma unroll
    for (int k = 0; k < 8; ++k) zv[k] = z4[lane + 64 * k];

    // stable LSE over the row of (z - g)
    float m = -3.402823466e+38f;
#pragma unroll
    for (int k = 0; k < 8; ++k) {
      m = fmaxf(m, fmaxf(fmaxf(zv[k].x - gv[k].x, zv[k].y - gv[k].y),
                         fmaxf(zv[k].z - gv[k].z, zv[k].w - gv[k].w)));
    }
    m = wave_max(m);

    float s = 0.f;
#pragma unroll
    for (int k = 0; k < 8; ++k) {
      s += __expf(zv[k].x - gv[k].x - m);
      s += __expf(zv[k].y - gv[k].y - m);
      s += __expf(zv[k].z - gv[k].z - m);
      s += __expf(zv[k].w - gv[k].w - m);
    }
    s = wave_sum(s);

    const float fr = m + __logf(s);
    if (lane == 0) f[(size_t)b * N + row] = fr;

    // column partials for the next col-normalize: exp(z0 - f)
#pragma unroll
    for (int k = 0; k < 8; ++k) {
      acc[k].x += __expf(zv[k].x - fr);
      acc[k].y += __expf(zv[k].y - fr);
      acc[k].z += __expf(zv[k].z - fr);
      acc[k].w += __expf(zv[k].w - fr);
    }
  }

  float4* p4 = reinterpret_cast<float4*>(part + ((size_t)b * CH + chunk) * N);
#pragma unroll
  for (int k = 0; k < 8; ++k) p4[lane + 64 * k] = acc[k];
}

// g_j = log( sum over CH chunk-partials ). One thread per (batch, column).
template <int CH>
__global__ void sink_combine_kernel(const float* __restrict__ part,
                                    float* __restrict__ g) {
  const int idx = blockIdx.x * blockDim.x + threadIdx.x;
  if (idx >= BATCH * N) return;
  const int b = idx / N;
  const int j = idx - b * N;
  const float* p = part + (size_t)b * CH * N + j;
  float s = 0.f;
#pragma unroll 8
  for (int c = 0; c < CH; ++c) s += p[(size_t)c * N];
  g[idx] = __logf(s);
}

__global__ __launch_bounds__(256) void sink_final_kernel(
    const float* __restrict__ z0, const float* __restrict__ f,
    const float* __restrict__ g, float* __restrict__ out) {
  const int b = blockIdx.y;
  const int row = blockIdx.x;
  const float fr = f[(size_t)b * N + row];
  const float4* z4 =
      reinterpret_cast<const float4*>(z0 + ((size_t)b * N + row) * N);
  const float4* g4 = reinterpret_cast<const float4*>(g + (size_t)b * N);
  float4* o4 = reinterpret_cast<float4*>(out + ((size_t)b * N + row) * N);
#pragma unroll
  for (int k = 0; k < 2; ++k) {
    const int i = threadIdx.x + 256 * k;
    const float4 z = z4[i];
    const float4 gg = g4[i];
    float4 r;
    r.x = __expf(z.x - fr - gg.x);
    r.y = __expf(z.y - fr - gg.y);
    r.z = __expf(z.z - fr - gg.z);
    r.w = __expf(z.w - fr - gg.w);
    o4[i] = r;
  }
}

extern "C" void kernel_launch(void* const* d_in, const int* in_sizes, int n_in,
                              void* d_out, int out_size, void* d_ws,
                              size_t ws_size, hipStream_t stream) {
  const float* z0 = (const float*)d_in[0];
  float* out = (float*)d_out;

  float* f = (float*)d_ws;                 // BATCH*N floats
  float* g = f + (size_t)BATCH * N;        // BATCH*N floats
  float* part = g + (size_t)BATCH * N;     // BATCH*CH*N floats

  const size_t base_bytes = 2ull * BATCH * N * sizeof(float);
  const size_t part8 = (size_t)BATCH * (N / 8) * N * sizeof(float);    // 16 MiB
  const size_t part32 = (size_t)BATCH * (N / 32) * N * sizeof(float);  // 4 MiB

  init_g_kernel<<<dim3((BATCH * N + 255) / 256), dim3(256), 0, stream>>>(g);

  if (ws_size >= base_bytes + part8) {
    constexpr int RPW = 8;
    constexpr int CH = N / RPW;
    for (int it = 0; it < NITERS; ++it) {
      sink_row_kernel<RPW>
          <<<dim3(N / (4 * RPW), BATCH), dim3(256), 0, stream>>>(z0, g, f,
                                                                 part);
      sink_combine_kernel<CH>
          <<<dim3((BATCH * N) / 64), dim3(64), 0, stream>>>(part, g);
    }
  } else if (ws_size >= base_bytes + part32) {
    constexpr int RPW = 32;
    constexpr int CH = N / RPW;
    for (int it = 0; it < NITERS; ++it) {
      sink_row_kernel<RPW>
          <<<dim3(N / (4 * RPW), BATCH), dim3(256), 0, stream>>>(z0, g, f,
                                                                 part);
      sink_combine_kernel<CH>
          <<<dim3((BATCH * N) / 64), dim3(64), 0, stream>>>(part, g);
    }
  } else {
    constexpr int RPW = 128;  // minimal-workspace fallback (~1.1 MiB)
    constexpr int CH = N / RPW;
    for (int it = 0; it < NITERS; ++it) {
      sink_row_kernel<RPW>
          <<<dim3(N / (4 * RPW), BATCH), dim3(256), 0, stream>>>(z0, g, f,
                                                                 part);
      sink_combine_kernel<CH>
          <<<dim3((BATCH * N) / 64), dim3(64), 0, stream>>>(part, g);
    }
  }

  sink_final_kernel<<<dim3(N, BATCH), dim3(256), 0, stream>>>(z0, f, g, out);
}